// Round 2
// baseline (18167.151 us; speedup 1.0000x reference)
//
#include <hip/hip_runtime.h>
#include <hip/hip_bf16.h>
#include <math.h>

// Problem constants
#define B_SZ 8
#define S_LEN 512
#define T_LEN 512
#define DIM 1024
#define HEADS 16
#define DH 64
#define MLP_DIM 4096

// ---------------------------------------------------------------------------
// Tiled fp32 GEMM: C[M,N] = A[M,K] @ W[K,N] + bias, optional GELU epilogue.
// 64x64 tile, BK=32, 256 threads, 4x4 accum per thread.
// LDS tiles stored k-major with 68-float row pitch (272B, 16B-aligned) so
// both fragments are contiguous float4 -> ds_read_b128.
// ---------------------------------------------------------------------------
template <int ACT>  // 0 = none, 1 = exact GELU
__global__ __launch_bounds__(256) void gemm_f32(
    const float* __restrict__ A, const float* __restrict__ W,
    const float* __restrict__ bias, float* __restrict__ C,
    int M, int N, int K) {
  __shared__ float Ast[32][68];  // [k][m]
  __shared__ float Ws[32][68];   // [k][n]
  const int m0 = blockIdx.y * 64;
  const int n0 = blockIdx.x * 64;
  const int tid = threadIdx.x;
  const int ty = tid >> 4;   // 0..15
  const int tx = tid & 15;   // 0..15
  float acc[4][4] = {};

  for (int k0 = 0; k0 < K; k0 += 32) {
    #pragma unroll
    for (int i = tid; i < 2048; i += 256) {
      int r = i >> 5, c = i & 31;                 // r: m-row 0..63, c: k 0..31
      Ast[c][r] = A[(size_t)(m0 + r) * K + (k0 + c)];
    }
    #pragma unroll
    for (int i = tid; i < 2048; i += 256) {
      int r = i >> 6, c = i & 63;                 // r: k 0..31, c: n 0..63
      Ws[r][c] = W[(size_t)(k0 + r) * N + (n0 + c)];
    }
    __syncthreads();
    #pragma unroll
    for (int kk = 0; kk < 32; kk++) {
      const float4 av = *reinterpret_cast<const float4*>(&Ast[kk][ty * 4]);
      const float4 wv = *reinterpret_cast<const float4*>(&Ws[kk][tx * 4]);
      const float a[4] = {av.x, av.y, av.z, av.w};
      const float w[4] = {wv.x, wv.y, wv.z, wv.w};
      #pragma unroll
      for (int i = 0; i < 4; i++)
        #pragma unroll
        for (int j = 0; j < 4; j++)
          acc[i][j] = fmaf(a[i], w[j], acc[i][j]);
    }
    __syncthreads();
  }

  const float4 bv = *reinterpret_cast<const float4*>(&bias[n0 + tx * 4]);
  const float bb[4] = {bv.x, bv.y, bv.z, bv.w};
  #pragma unroll
  for (int i = 0; i < 4; i++) {
    const int r = m0 + ty * 4 + i;
    float4 o;
    float* op = &o.x;
    #pragma unroll
    for (int j = 0; j < 4; j++) {
      float v = acc[i][j] + bb[j];
      if (ACT == 1) v = 0.5f * v * (1.0f + erff(v * 0.70710678118654752f));
      op[j] = v;
    }
    *reinterpret_cast<float4*>(&C[(size_t)r * N + n0 + tx * 4]) = o;
  }
}

// ---------------------------------------------------------------------------
// Gate GEMM: g = sigmoid([X | Y] @ Wg + bg);  h = X + g*Y  written into the
// fused buffer at row b*1024 + seg*512 + s.  X,Y: [4096,1024]; Wg: [2048,1024].
// ---------------------------------------------------------------------------
__global__ __launch_bounds__(256) void gemm_gate_f32(
    const float* __restrict__ X, const float* __restrict__ Y,
    const float* __restrict__ W, const float* __restrict__ bias,
    float* __restrict__ FUS, int seg) {
  const int N = 1024, K = 2048;
  __shared__ float Ast[32][68];
  __shared__ float Ws[32][68];
  const int m0 = blockIdx.y * 64;
  const int n0 = blockIdx.x * 64;
  const int tid = threadIdx.x;
  const int ty = tid >> 4;
  const int tx = tid & 15;
  float acc[4][4] = {};

  for (int k0 = 0; k0 < K; k0 += 32) {
    #pragma unroll
    for (int i = tid; i < 2048; i += 256) {
      int r = i >> 5, c = i & 31;
      int kg = k0 + c;
      Ast[c][r] = (kg < 1024) ? X[(size_t)(m0 + r) * 1024 + kg]
                              : Y[(size_t)(m0 + r) * 1024 + (kg - 1024)];
    }
    #pragma unroll
    for (int i = tid; i < 2048; i += 256) {
      int r = i >> 6, c = i & 63;
      Ws[r][c] = W[(size_t)(k0 + r) * N + (n0 + c)];
    }
    __syncthreads();
    #pragma unroll
    for (int kk = 0; kk < 32; kk++) {
      const float4 av = *reinterpret_cast<const float4*>(&Ast[kk][ty * 4]);
      const float4 wv = *reinterpret_cast<const float4*>(&Ws[kk][tx * 4]);
      const float a[4] = {av.x, av.y, av.z, av.w};
      const float w[4] = {wv.x, wv.y, wv.z, wv.w};
      #pragma unroll
      for (int i = 0; i < 4; i++)
        #pragma unroll
        for (int j = 0; j < 4; j++)
          acc[i][j] = fmaf(a[i], w[j], acc[i][j]);
    }
    __syncthreads();
  }

  const float4 bv = *reinterpret_cast<const float4*>(&bias[n0 + tx * 4]);
  const float bb[4] = {bv.x, bv.y, bv.z, bv.w};
  #pragma unroll
  for (int i = 0; i < 4; i++) {
    const int r = m0 + ty * 4 + i;                      // 0..4095  (b*512 + s)
    const int dr = ((r >> 9) << 10) | (seg << 9) | (r & 511);
    const float4 x4 = *reinterpret_cast<const float4*>(&X[(size_t)r * 1024 + n0 + tx * 4]);
    const float4 y4 = *reinterpret_cast<const float4*>(&Y[(size_t)r * 1024 + n0 + tx * 4]);
    const float xs[4] = {x4.x, x4.y, x4.z, x4.w};
    const float ys[4] = {y4.x, y4.y, y4.z, y4.w};
    float4 o;
    float* op = &o.x;
    #pragma unroll
    for (int j = 0; j < 4; j++) {
      float g = acc[i][j] + bb[j];
      g = 1.0f / (1.0f + __expf(-g));
      op[j] = xs[j] + g * ys[j];
    }
    *reinterpret_cast<float4*>(&FUS[(size_t)dr * 1024 + n0 + tx * 4]) = o;
  }
}

// ---------------------------------------------------------------------------
// Flash-style attention: one wave per (b, h, q) row; lane = head-dim element.
// Online softmax per segment; segments weighted by *wsp / *wtp when 2 segs.
// ---------------------------------------------------------------------------
__global__ __launch_bounds__(256) void attn_f32(
    const float* __restrict__ Q, const float* __restrict__ K,
    const float* __restrict__ V, float* __restrict__ O,
    int Sq, int Sk, int seglen,
    const float* __restrict__ wsp, const float* __restrict__ wtp) {
  const int wib = threadIdx.x >> 6;
  const int lane = threadIdx.x & 63;
  const long wg = (long)blockIdx.x * 4 + wib;
  const int q = (int)(wg % Sq);
  const int h = (int)((wg / Sq) % HEADS);
  const int b = (int)(wg / ((long)Sq * HEADS));

  const float qd = Q[((size_t)(b * Sq + q)) * 1024 + h * 64 + lane];
  const float* kb = K + ((size_t)b * Sk) * 1024 + h * 64;
  const float* vb = V + ((size_t)b * Sk) * 1024 + h * 64;

  const int nseg = (seglen == Sk) ? 1 : 2;
  float outv = 0.0f;

  for (int sg = 0; sg < nseg; sg++) {
    const int kbeg = sg * seglen;
    float m = -1e30f, l = 0.0f, acc = 0.0f;
    for (int k = kbeg; k < kbeg + seglen; k++) {
      float s = qd * kb[(size_t)k * 1024 + lane];
      #pragma unroll
      for (int o = 32; o >= 1; o >>= 1) s += __shfl_xor(s, o);
      s *= 0.125f;  // 1/sqrt(64)
      const float mn = fmaxf(m, s);
      const float corr = __expf(m - mn);
      const float p = __expf(s - mn);
      l = l * corr + p;
      acc = acc * corr + p * vb[(size_t)k * 1024 + lane];
      m = mn;
    }
    float w = 1.0f;
    if (nseg == 2) w = (sg == 0) ? *wsp : *wtp;
    outv += w * acc / l;
  }
  O[((size_t)(b * Sq + q)) * 1024 + h * 64 + lane] = outv;
}

// ---------------------------------------------------------------------------
// LayerNorm over 1024 cols of (X + Y), one row per 256-thread block.
// mode 0: out[row].  mode 1: split rows b*1024+s into the two outputs.
// ---------------------------------------------------------------------------
__global__ __launch_bounds__(256) void ln_f32(
    const float* __restrict__ X, const float* __restrict__ Y,
    const float* __restrict__ g, const float* __restrict__ bb,
    float* __restrict__ out, int mode) {
  __shared__ float sm[4];
  const int row = blockIdx.x;
  const int tid = threadIdx.x;

  float v[4];
  #pragma unroll
  for (int i = 0; i < 4; i++) {
    const int c = tid + i * 256;
    v[i] = X[(size_t)row * 1024 + c] + Y[(size_t)row * 1024 + c];
  }
  float s = v[0] + v[1] + v[2] + v[3];
  #pragma unroll
  for (int o = 32; o >= 1; o >>= 1) s += __shfl_xor(s, o);
  if ((tid & 63) == 0) sm[tid >> 6] = s;
  __syncthreads();
  const float mu = (sm[0] + sm[1] + sm[2] + sm[3]) * (1.0f / 1024.0f);
  __syncthreads();

  float d2 = 0.0f;
  #pragma unroll
  for (int i = 0; i < 4; i++) {
    const float d = v[i] - mu;
    d2 += d * d;
  }
  #pragma unroll
  for (int o = 32; o >= 1; o >>= 1) d2 += __shfl_xor(d2, o);
  if ((tid & 63) == 0) sm[tid >> 6] = d2;
  __syncthreads();
  const float var = (sm[0] + sm[1] + sm[2] + sm[3]) * (1.0f / 1024.0f);
  const float rstd = rsqrtf(var + 1e-12f);

  float* dst;
  if (mode == 0) {
    dst = out + (size_t)row * 1024;
  } else {
    const int b = row >> 10;
    const int sdx = row & 1023;
    if (sdx < 512)
      dst = out + ((size_t)(b * 512 + sdx)) * 1024;
    else
      dst = out + (size_t)B_SZ * S_LEN * DIM + ((size_t)(b * 512 + (sdx - 512))) * 1024;
  }
  #pragma unroll
  for (int i = 0; i < 4; i++) {
    const int c = tid + i * 256;
    dst[c] = (v[i] - mu) * rstd * g[c] + bb[c];
  }
}

// ---------------------------------------------------------------------------
// Workspace: 4 buffers of [8192,1024] fp32 = 128 MiB total.  d_out (exactly
// 8192*1024 floats) is additionally used as scratch for the self-attn output;
// it is fully overwritten by the final LN2 split-write.
// ---------------------------------------------------------------------------
extern "C" void kernel_launch(void* const* d_in, const int* in_sizes, int n_in,
                              void* d_out, int out_size, void* d_ws, size_t ws_size,
                              hipStream_t stream) {
  const float* src = (const float*)d_in[0];
  const float* tgt = (const float*)d_in[1];
  const float* Wq = (const float*)d_in[2];
  const float* bq = (const float*)d_in[3];
  const float* Wk = (const float*)d_in[4];
  const float* bk = (const float*)d_in[5];
  const float* Wv = (const float*)d_in[6];
  const float* bv = (const float*)d_in[7];
  const float* Wd = (const float*)d_in[8];
  const float* bd = (const float*)d_in[9];
  const float* ln1g = (const float*)d_in[10];
  const float* ln1b = (const float*)d_in[11];
  const float* wsp = (const float*)d_in[12];
  const float* wtp = (const float*)d_in[13];
  const float* Wgs = (const float*)d_in[14];
  const float* bgs = (const float*)d_in[15];
  const float* Wgt = (const float*)d_in[16];
  const float* bgt = (const float*)d_in[17];
  const float* W1 = (const float*)d_in[18];
  const float* b1 = (const float*)d_in[19];
  const float* W2 = (const float*)d_in[20];
  const float* b2 = (const float*)d_in[21];
  const float* ln2g = (const float*)d_in[22];
  const float* ln2b = (const float*)d_in[23];

  const size_t M1 = (size_t)4096 * 1024;   // half-buffer (4096 rows)
  const size_t BUF = 2 * M1;               // full buffer (8192 rows)
  float* Buf0 = (float*)d_ws;
  float* Buf1 = Buf0 + BUF;
  float* Buf2 = Buf1 + BUF;
  float* Buf3 = Buf2 + BUF;
  float* DOUT = (float*)d_out;             // scratch for AO, final output

  const dim3 blk(256);
  const dim3 gP(16, 64);    // M=4096, N=1024
  const dim3 gF(16, 128);   // M=8192, N=1024
  const dim3 gW1(64, 32);   // M=2048, N=4096
  const dim3 gW2(16, 32);   // M=2048, N=1024

  // 1. cross projections (shared Wq/Wk/Wv): Q->Buf0, K->Buf1, V->Buf2
  gemm_f32<0><<<gP, blk, 0, stream>>>(src, Wq, bq, Buf0,      4096, 1024, 1024);
  gemm_f32<0><<<gP, blk, 0, stream>>>(tgt, Wq, bq, Buf0 + M1, 4096, 1024, 1024);
  gemm_f32<0><<<gP, blk, 0, stream>>>(src, Wk, bk, Buf1,      4096, 1024, 1024);
  gemm_f32<0><<<gP, blk, 0, stream>>>(tgt, Wk, bk, Buf1 + M1, 4096, 1024, 1024);
  gemm_f32<0><<<gP, blk, 0, stream>>>(src, Wv, bv, Buf2,      4096, 1024, 1024);
  gemm_f32<0><<<gP, blk, 0, stream>>>(tgt, Wv, bv, Buf2 + M1, 4096, 1024, 1024);

  // 2. cross attention: s_t -> Buf3 lower, t_s -> Buf3 upper
  const int xblocks = B_SZ * HEADS * 512 / 4;
  attn_f32<<<xblocks, blk, 0, stream>>>(Buf0,      Buf1 + M1, Buf2 + M1, Buf3,      512, 512, 512, nullptr, nullptr);
  attn_f32<<<xblocks, blk, 0, stream>>>(Buf0 + M1, Buf1,      Buf2,      Buf3 + M1, 512, 512, 512, nullptr, nullptr);

  // 3. gates + residual -> FUS in Buf0 (Q projections dead)
  gemm_gate_f32<<<gP, blk, 0, stream>>>(src, Buf3,      Wgs, bgs, Buf0, 0);
  gemm_gate_f32<<<gP, blk, 0, stream>>>(tgt, Buf3 + M1, Wgt, bgt, Buf0, 1);

  // 4. self projections: qf->Buf1, kf->Buf2, vf->Buf3
  gemm_f32<0><<<gF, blk, 0, stream>>>(Buf0, Wq, bq, Buf1, 8192, 1024, 1024);
  gemm_f32<0><<<gF, blk, 0, stream>>>(Buf0, Wk, bk, Buf2, 8192, 1024, 1024);
  gemm_f32<0><<<gF, blk, 0, stream>>>(Buf0, Wv, bv, Buf3, 8192, 1024, 1024);

  // 5. self attention (segment-weighted softmax) -> DOUT (scratch)
  const int sblocks = B_SZ * HEADS * 1024 / 4;
  attn_f32<<<sblocks, blk, 0, stream>>>(Buf1, Buf2, Buf3, DOUT, 1024, 1024, 512, wsp, wtp);

  // 6. ctx -> Buf1 (qf dead)
  gemm_f32<0><<<gF, blk, 0, stream>>>(DOUT, Wd, bd, Buf1, 8192, 1024, 1024);

  // 7. hidden = LN1(ctx + fused) -> Buf2 (kf dead)
  ln_f32<<<8192, blk, 0, stream>>>(Buf1, Buf0, ln1g, ln1b, Buf2, 0);

  // 8. MLP, chunked over 4 x 2048 rows; mid -> Buf3 (vf dead), ff -> Buf1
  for (int ch = 0; ch < 4; ch++) {
    const size_t ro = (size_t)ch * 2048 * 1024;
    gemm_f32<1><<<gW1, blk, 0, stream>>>(Buf2 + ro, W1, b1, Buf3, 2048, 4096, 1024);
    gemm_f32<0><<<gW2, blk, 0, stream>>>(Buf3, W2, b2, Buf1 + ro, 2048, 1024, 4096);
  }

  // 9. LN2(ff + hidden) -> split outputs
  ln_f32<<<8192, blk, 0, stream>>>(Buf1, Buf2, ln2g, ln2b, DOUT, 1);
}

// Round 3
// 7532.328 us; speedup vs baseline: 2.4119x; 2.4119x over previous
//
#include <hip/hip_runtime.h>
#include <hip/hip_bf16.h>
#include <math.h>

// Problem constants
#define B_SZ 8
#define S_LEN 512
#define T_LEN 512
#define DIM 1024
#define HEADS 16
#define DH 64
#define MLP_DIM 4096

// ---------------------------------------------------------------------------
// Tiled fp32 GEMM: C[M,N] = A[M,K] @ W[K,N] + bias, optional GELU epilogue.
// 64x64 tile, BK=32, 256 threads, 4x4 accum per thread.
// ---------------------------------------------------------------------------
template <int ACT>  // 0 = none, 1 = exact GELU
__global__ __launch_bounds__(256) void gemm_f32(
    const float* __restrict__ A, const float* __restrict__ W,
    const float* __restrict__ bias, float* __restrict__ C,
    int M, int N, int K) {
  __shared__ float Ast[32][68];  // [k][m]
  __shared__ float Ws[32][68];   // [k][n]
  const int m0 = blockIdx.y * 64;
  const int n0 = blockIdx.x * 64;
  const int tid = threadIdx.x;
  const int ty = tid >> 4;   // 0..15
  const int tx = tid & 15;   // 0..15
  float acc[4][4] = {};

  for (int k0 = 0; k0 < K; k0 += 32) {
    #pragma unroll
    for (int i = tid; i < 2048; i += 256) {
      int r = i >> 5, c = i & 31;                 // r: m-row 0..63, c: k 0..31
      Ast[c][r] = A[(size_t)(m0 + r) * K + (k0 + c)];
    }
    #pragma unroll
    for (int i = tid; i < 2048; i += 256) {
      int r = i >> 6, c = i & 63;                 // r: k 0..31, c: n 0..63
      Ws[r][c] = W[(size_t)(k0 + r) * N + (n0 + c)];
    }
    __syncthreads();
    #pragma unroll
    for (int kk = 0; kk < 32; kk++) {
      const float4 av = *reinterpret_cast<const float4*>(&Ast[kk][ty * 4]);
      const float4 wv = *reinterpret_cast<const float4*>(&Ws[kk][tx * 4]);
      const float a[4] = {av.x, av.y, av.z, av.w};
      const float w[4] = {wv.x, wv.y, wv.z, wv.w};
      #pragma unroll
      for (int i = 0; i < 4; i++)
        #pragma unroll
        for (int j = 0; j < 4; j++)
          acc[i][j] = fmaf(a[i], w[j], acc[i][j]);
    }
    __syncthreads();
  }

  const float4 bv = *reinterpret_cast<const float4*>(&bias[n0 + tx * 4]);
  const float bb[4] = {bv.x, bv.y, bv.z, bv.w};
  #pragma unroll
  for (int i = 0; i < 4; i++) {
    const int r = m0 + ty * 4 + i;
    float4 o;
    float* op = &o.x;
    #pragma unroll
    for (int j = 0; j < 4; j++) {
      float v = acc[i][j] + bb[j];
      if (ACT == 1) v = 0.5f * v * (1.0f + erff(v * 0.70710678118654752f));
      op[j] = v;
    }
    *reinterpret_cast<float4*>(&C[(size_t)r * N + n0 + tx * 4]) = o;
  }
}

// ---------------------------------------------------------------------------
// Gate GEMM: g = sigmoid([X | Y] @ Wg + bg);  h = X + g*Y  written into the
// fused buffer at row b*1024 + seg*512 + s.  X,Y: [4096,1024]; Wg: [2048,1024].
// ---------------------------------------------------------------------------
__global__ __launch_bounds__(256) void gemm_gate_f32(
    const float* __restrict__ X, const float* __restrict__ Y,
    const float* __restrict__ W, const float* __restrict__ bias,
    float* __restrict__ FUS, int seg) {
  const int N = 1024, K = 2048;
  __shared__ float Ast[32][68];
  __shared__ float Ws[32][68];
  const int m0 = blockIdx.y * 64;
  const int n0 = blockIdx.x * 64;
  const int tid = threadIdx.x;
  const int ty = tid >> 4;
  const int tx = tid & 15;
  float acc[4][4] = {};

  for (int k0 = 0; k0 < K; k0 += 32) {
    #pragma unroll
    for (int i = tid; i < 2048; i += 256) {
      int r = i >> 5, c = i & 31;
      int kg = k0 + c;
      Ast[c][r] = (kg < 1024) ? X[(size_t)(m0 + r) * 1024 + kg]
                              : Y[(size_t)(m0 + r) * 1024 + (kg - 1024)];
    }
    #pragma unroll
    for (int i = tid; i < 2048; i += 256) {
      int r = i >> 6, c = i & 63;
      Ws[r][c] = W[(size_t)(k0 + r) * N + (n0 + c)];
    }
    __syncthreads();
    #pragma unroll
    for (int kk = 0; kk < 32; kk++) {
      const float4 av = *reinterpret_cast<const float4*>(&Ast[kk][ty * 4]);
      const float4 wv = *reinterpret_cast<const float4*>(&Ws[kk][tx * 4]);
      const float a[4] = {av.x, av.y, av.z, av.w};
      const float w[4] = {wv.x, wv.y, wv.z, wv.w};
      #pragma unroll
      for (int i = 0; i < 4; i++)
        #pragma unroll
        for (int j = 0; j < 4; j++)
          acc[i][j] = fmaf(a[i], w[j], acc[i][j]);
    }
    __syncthreads();
  }

  const float4 bv = *reinterpret_cast<const float4*>(&bias[n0 + tx * 4]);
  const float bb[4] = {bv.x, bv.y, bv.z, bv.w};
  #pragma unroll
  for (int i = 0; i < 4; i++) {
    const int r = m0 + ty * 4 + i;                      // 0..4095  (b*512 + s)
    const int dr = ((r >> 9) << 10) | (seg << 9) | (r & 511);
    const float4 x4 = *reinterpret_cast<const float4*>(&X[(size_t)r * 1024 + n0 + tx * 4]);
    const float4 y4 = *reinterpret_cast<const float4*>(&Y[(size_t)r * 1024 + n0 + tx * 4]);
    const float xs[4] = {x4.x, x4.y, x4.z, x4.w};
    const float ys[4] = {y4.x, y4.y, y4.z, y4.w};
    float4 o;
    float* op = &o.x;
    #pragma unroll
    for (int j = 0; j < 4; j++) {
      float g = acc[i][j] + bb[j];
      g = 1.0f / (1.0f + __expf(-g));
      op[j] = xs[j] + g * ys[j];
    }
    *reinterpret_cast<float4*>(&FUS[(size_t)dr * 1024 + n0 + tx * 4]) = o;
  }
}

// ---------------------------------------------------------------------------
// Tiled flash attention (fp32). Block = 256 threads handles 64 q-rows of one
// (b,h). K/V staged in LDS 64-key tiles (time-shared buffer); P redistributed
// through LDS for the PV GEMM. Per-thread 4x4 fragments; k-fragment indices
// strided by 16 for bank-conflict-free ds_read_b128.
// Online softmax per segment; segment results weighted by *wsp / *wtp when
// there are two segments (self-attn), weight 1 otherwise.
// ---------------------------------------------------------------------------
__global__ __launch_bounds__(256) void attn_tile_f32(
    const float* __restrict__ Q, const float* __restrict__ K,
    const float* __restrict__ V, float* __restrict__ O,
    int Sq, int Sk, int seglen,
    const float* __restrict__ wsp, const float* __restrict__ wtp) {
  __shared__ float Qs[64][68];
  __shared__ float KVs[64][68];
  __shared__ float Ps[64][68];

  const int tid = threadIdx.x;
  const int ty = tid >> 4;   // 0..15 : q-group (4 rows)
  const int tx = tid & 15;   // 0..15 : k/d-group

  const int nqt = Sq >> 6;
  const int qt = blockIdx.x % nqt;
  const int h  = (blockIdx.x / nqt) % HEADS;
  const int b  = blockIdx.x / (nqt * HEADS);

  const size_t qbase = ((size_t)b * Sq + qt * 64) * 1024 + h * 64;
  const size_t kbase = ((size_t)b * Sk) * 1024 + h * 64;

  // Load Q tile, scale folded in (1/sqrt(64) = 0.125)
  #pragma unroll
  for (int i = tid; i < 1024; i += 256) {
    const int r = i >> 4, c4 = (i & 15) * 4;
    float4 v4 = *reinterpret_cast<const float4*>(&Q[qbase + (size_t)r * 1024 + c4]);
    Qs[r][c4 + 0] = v4.x * 0.125f;
    Qs[r][c4 + 1] = v4.y * 0.125f;
    Qs[r][c4 + 2] = v4.z * 0.125f;
    Qs[r][c4 + 3] = v4.w * 0.125f;
  }

  float m[4], l[4], acc[4][4] = {}, out[4][4] = {};
  #pragma unroll
  for (int i = 0; i < 4; i++) { m[i] = -1e30f; l[i] = 0.0f; }

  const int ntile = Sk >> 6;
  const int tps = seglen >> 6;  // tiles per segment

  for (int t = 0; t < ntile; t++) {
    const size_t kt = kbase + (size_t)t * 64 * 1024;
    __syncthreads();  // prev GEMM-2 reads done (and Qs ready on t=0)
    #pragma unroll
    for (int i = tid; i < 1024; i += 256) {
      const int r = i >> 4, c4 = (i & 15) * 4;
      *reinterpret_cast<float4*>(&KVs[r][c4]) =
          *reinterpret_cast<const float4*>(&K[kt + (size_t)r * 1024 + c4]);
    }
    __syncthreads();

    // GEMM-1: s[i][jj] = sum_d Qs[ty*4+i][d] * K[tx+16*jj][d]
    float s[4][4] = {};
    #pragma unroll
    for (int d0 = 0; d0 < 64; d0 += 4) {
      float4 q4[4], k4[4];
      #pragma unroll
      for (int i = 0; i < 4; i++) q4[i] = *reinterpret_cast<const float4*>(&Qs[ty * 4 + i][d0]);
      #pragma unroll
      for (int jj = 0; jj < 4; jj++) k4[jj] = *reinterpret_cast<const float4*>(&KVs[tx + 16 * jj][d0]);
      #pragma unroll
      for (int i = 0; i < 4; i++)
        #pragma unroll
        for (int jj = 0; jj < 4; jj++) {
          s[i][jj] = fmaf(q4[i].x, k4[jj].x, s[i][jj]);
          s[i][jj] = fmaf(q4[i].y, k4[jj].y, s[i][jj]);
          s[i][jj] = fmaf(q4[i].z, k4[jj].z, s[i][jj]);
          s[i][jj] = fmaf(q4[i].w, k4[jj].w, s[i][jj]);
        }
    }
    __syncthreads();  // K tile dead

    // Load V tile into the same buffer (latency overlaps softmax below)
    #pragma unroll
    for (int i = tid; i < 1024; i += 256) {
      const int r = i >> 4, c4 = (i & 15) * 4;
      *reinterpret_cast<float4*>(&KVs[r][c4]) =
          *reinterpret_cast<const float4*>(&V[kt + (size_t)r * 1024 + c4]);
    }

    // Online softmax over this tile (row = ty*4+i, cols tx+16*jj)
    float corr[4];
    #pragma unroll
    for (int i = 0; i < 4; i++) {
      float rm = fmaxf(fmaxf(s[i][0], s[i][1]), fmaxf(s[i][2], s[i][3]));
      #pragma unroll
      for (int o = 1; o < 16; o <<= 1) rm = fmaxf(rm, __shfl_xor(rm, o));
      const float mn = fmaxf(m[i], rm);
      corr[i] = __expf(m[i] - mn);
      float ls = 0.0f;
      #pragma unroll
      for (int jj = 0; jj < 4; jj++) {
        s[i][jj] = __expf(s[i][jj] - mn);
        ls += s[i][jj];
      }
      #pragma unroll
      for (int o = 1; o < 16; o <<= 1) ls += __shfl_xor(ls, o);
      l[i] = l[i] * corr[i] + ls;
      m[i] = mn;
      #pragma unroll
      for (int jj = 0; jj < 4; jj++) Ps[ty * 4 + i][tx + 16 * jj] = s[i][jj];
    }
    __syncthreads();  // V + Ps ready

    // GEMM-2: acc = acc*corr + P @ V
    #pragma unroll
    for (int i = 0; i < 4; i++)
      #pragma unroll
      for (int j = 0; j < 4; j++) acc[i][j] *= corr[i];
    #pragma unroll
    for (int k0 = 0; k0 < 64; k0 += 4) {
      float4 p4[4], v4[4];
      #pragma unroll
      for (int i = 0; i < 4; i++) p4[i] = *reinterpret_cast<const float4*>(&Ps[ty * 4 + i][k0]);
      #pragma unroll
      for (int t2 = 0; t2 < 4; t2++) v4[t2] = *reinterpret_cast<const float4*>(&KVs[k0 + t2][tx * 4]);
      #pragma unroll
      for (int i = 0; i < 4; i++) {
        const float* vp0 = &v4[0].x;
        #pragma unroll
        for (int j = 0; j < 4; j++) {
          float a = fmaf(p4[i].x, (&v4[0].x)[j], 0.0f);
          a = fmaf(p4[i].y, (&v4[1].x)[j], a);
          a = fmaf(p4[i].z, (&v4[2].x)[j], a);
          a = fmaf(p4[i].w, (&v4[3].x)[j], a);
          acc[i][j] += a;
        }
        (void)vp0;
      }
    }

    // Segment flush
    if (((t + 1) % tps) == 0) {
      float w = 1.0f;
      if (ntile != tps) w = ((t + 1) / tps == 1) ? *wsp : *wtp;
      #pragma unroll
      for (int i = 0; i < 4; i++) {
        const float inv = w / l[i];
        #pragma unroll
        for (int j = 0; j < 4; j++) {
          out[i][j] += acc[i][j] * inv;
          acc[i][j] = 0.0f;
        }
        m[i] = -1e30f;
        l[i] = 0.0f;
      }
    }
  }

  #pragma unroll
  for (int i = 0; i < 4; i++) {
    float4 o4;
    o4.x = out[i][0]; o4.y = out[i][1]; o4.z = out[i][2]; o4.w = out[i][3];
    *reinterpret_cast<float4*>(&O[qbase + (size_t)(ty * 4 + i) * 1024 + tx * 4]) = o4;
  }
}

// ---------------------------------------------------------------------------
// LayerNorm over 1024 cols of (X + Y), one row per 256-thread block.
// mode 0: out[row].  mode 1: split rows b*1024+s into the two outputs.
// ---------------------------------------------------------------------------
__global__ __launch_bounds__(256) void ln_f32(
    const float* __restrict__ X, const float* __restrict__ Y,
    const float* __restrict__ g, const float* __restrict__ bb,
    float* __restrict__ out, int mode) {
  __shared__ float sm[4];
  const int row = blockIdx.x;
  const int tid = threadIdx.x;

  float v[4];
  #pragma unroll
  for (int i = 0; i < 4; i++) {
    const int c = tid + i * 256;
    v[i] = X[(size_t)row * 1024 + c] + Y[(size_t)row * 1024 + c];
  }
  float s = v[0] + v[1] + v[2] + v[3];
  #pragma unroll
  for (int o = 32; o >= 1; o >>= 1) s += __shfl_xor(s, o);
  if ((tid & 63) == 0) sm[tid >> 6] = s;
  __syncthreads();
  const float mu = (sm[0] + sm[1] + sm[2] + sm[3]) * (1.0f / 1024.0f);
  __syncthreads();

  float d2 = 0.0f;
  #pragma unroll
  for (int i = 0; i < 4; i++) {
    const float d = v[i] - mu;
    d2 += d * d;
  }
  #pragma unroll
  for (int o = 32; o >= 1; o >>= 1) d2 += __shfl_xor(d2, o);
  if ((tid & 63) == 0) sm[tid >> 6] = d2;
  __syncthreads();
  const float var = (sm[0] + sm[1] + sm[2] + sm[3]) * (1.0f / 1024.0f);
  const float rstd = rsqrtf(var + 1e-12f);

  float* dst;
  if (mode == 0) {
    dst = out + (size_t)row * 1024;
  } else {
    const int b = row >> 10;
    const int sdx = row & 1023;
    if (sdx < 512)
      dst = out + ((size_t)(b * 512 + sdx)) * 1024;
    else
      dst = out + (size_t)B_SZ * S_LEN * DIM + ((size_t)(b * 512 + (sdx - 512))) * 1024;
  }
  #pragma unroll
  for (int i = 0; i < 4; i++) {
    const int c = tid + i * 256;
    dst[c] = (v[i] - mu) * rstd * g[c] + bb[c];
  }
}

// ---------------------------------------------------------------------------
// Workspace: 4 buffers of [8192,1024] fp32 = 128 MiB.  d_out used as scratch
// for the self-attn output (fully overwritten by the final LN2 split-write).
// ---------------------------------------------------------------------------
extern "C" void kernel_launch(void* const* d_in, const int* in_sizes, int n_in,
                              void* d_out, int out_size, void* d_ws, size_t ws_size,
                              hipStream_t stream) {
  const float* src = (const float*)d_in[0];
  const float* tgt = (const float*)d_in[1];
  const float* Wq = (const float*)d_in[2];
  const float* bq = (const float*)d_in[3];
  const float* Wk = (const float*)d_in[4];
  const float* bk = (const float*)d_in[5];
  const float* Wv = (const float*)d_in[6];
  const float* bv = (const float*)d_in[7];
  const float* Wd = (const float*)d_in[8];
  const float* bd = (const float*)d_in[9];
  const float* ln1g = (const float*)d_in[10];
  const float* ln1b = (const float*)d_in[11];
  const float* wsp = (const float*)d_in[12];
  const float* wtp = (const float*)d_in[13];
  const float* Wgs = (const float*)d_in[14];
  const float* bgs = (const float*)d_in[15];
  const float* Wgt = (const float*)d_in[16];
  const float* bgt = (const float*)d_in[17];
  const float* W1 = (const float*)d_in[18];
  const float* b1 = (const float*)d_in[19];
  const float* W2 = (const float*)d_in[20];
  const float* b2 = (const float*)d_in[21];
  const float* ln2g = (const float*)d_in[22];
  const float* ln2b = (const float*)d_in[23];

  const size_t M1 = (size_t)4096 * 1024;   // half-buffer (4096 rows)
  const size_t BUF = 2 * M1;               // full buffer (8192 rows)
  float* Buf0 = (float*)d_ws;
  float* Buf1 = Buf0 + BUF;
  float* Buf2 = Buf1 + BUF;
  float* Buf3 = Buf2 + BUF;
  float* DOUT = (float*)d_out;

  const dim3 blk(256);
  const dim3 gP(16, 64);    // M=4096, N=1024
  const dim3 gF(16, 128);   // M=8192, N=1024
  const dim3 gW1(64, 32);   // M=2048, N=4096
  const dim3 gW2(16, 32);   // M=2048, N=1024

  // 1. cross projections: Q->Buf0, K->Buf1, V->Buf2
  gemm_f32<0><<<gP, blk, 0, stream>>>(src, Wq, bq, Buf0,      4096, 1024, 1024);
  gemm_f32<0><<<gP, blk, 0, stream>>>(tgt, Wq, bq, Buf0 + M1, 4096, 1024, 1024);
  gemm_f32<0><<<gP, blk, 0, stream>>>(src, Wk, bk, Buf1,      4096, 1024, 1024);
  gemm_f32<0><<<gP, blk, 0, stream>>>(tgt, Wk, bk, Buf1 + M1, 4096, 1024, 1024);
  gemm_f32<0><<<gP, blk, 0, stream>>>(src, Wv, bv, Buf2,      4096, 1024, 1024);
  gemm_f32<0><<<gP, blk, 0, stream>>>(tgt, Wv, bv, Buf2 + M1, 4096, 1024, 1024);

  // 2. cross attention: s_t -> Buf3 lower, t_s -> Buf3 upper
  const int xblocks = B_SZ * HEADS * (512 / 64);
  attn_tile_f32<<<xblocks, blk, 0, stream>>>(Buf0,      Buf1 + M1, Buf2 + M1, Buf3,      512, 512, 512, wsp, wtp);
  attn_tile_f32<<<xblocks, blk, 0, stream>>>(Buf0 + M1, Buf1,      Buf2,      Buf3 + M1, 512, 512, 512, wsp, wtp);

  // 3. gates + residual -> FUS in Buf0
  gemm_gate_f32<<<gP, blk, 0, stream>>>(src, Buf3,      Wgs, bgs, Buf0, 0);
  gemm_gate_f32<<<gP, blk, 0, stream>>>(tgt, Buf3 + M1, Wgt, bgt, Buf0, 1);

  // 4. self projections: qf->Buf1, kf->Buf2, vf->Buf3
  gemm_f32<0><<<gF, blk, 0, stream>>>(Buf0, Wq, bq, Buf1, 8192, 1024, 1024);
  gemm_f32<0><<<gF, blk, 0, stream>>>(Buf0, Wk, bk, Buf2, 8192, 1024, 1024);
  gemm_f32<0><<<gF, blk, 0, stream>>>(Buf0, Wv, bv, Buf3, 8192, 1024, 1024);

  // 5. self attention (segment-weighted softmax) -> DOUT (scratch)
  const int sblocks = B_SZ * HEADS * (1024 / 64);
  attn_tile_f32<<<sblocks, blk, 0, stream>>>(Buf1, Buf2, Buf3, DOUT, 1024, 1024, 512, wsp, wtp);

  // 6. ctx -> Buf1
  gemm_f32<0><<<gF, blk, 0, stream>>>(DOUT, Wd, bd, Buf1, 8192, 1024, 1024);

  // 7. hidden = LN1(ctx + fused) -> Buf2
  ln_f32<<<8192, blk, 0, stream>>>(Buf1, Buf0, ln1g, ln1b, Buf2, 0);

  // 8. MLP, chunked over 4 x 2048 rows; mid -> Buf3, ff -> Buf1
  for (int ch = 0; ch < 4; ch++) {
    const size_t ro = (size_t)ch * 2048 * 1024;
    gemm_f32<1><<<gW1, blk, 0, stream>>>(Buf2 + ro, W1, b1, Buf3, 2048, 4096, 1024);
    gemm_f32<0><<<gW2, blk, 0, stream>>>(Buf3, W2, b2, Buf1 + ro, 2048, 1024, 4096);
  }

  // 9. LN2(ff + hidden) -> split outputs
  ln_f32<<<8192, blk, 0, stream>>>(Buf1, Buf2, ln2g, ln2b, DOUT, 1);
}

// Round 5
// 3010.598 us; speedup vs baseline: 6.0344x; 2.5019x over previous
//
#include <hip/hip_runtime.h>
#include <hip/hip_bf16.h>
#include <math.h>

#define B_SZ 8
#define S_LEN 512
#define T_LEN 512
#define DIM 1024
#define HEADS 16
#define DH 64
#define MLP_DIM 4096

typedef unsigned short ushort_t;
typedef unsigned int uint_t;
typedef short bf16x8 __attribute__((ext_vector_type(8)));
typedef float f32x4 __attribute__((ext_vector_type(4)));

// Round-to-nearest-even fp32 -> bf16 (top 16 bits)
__device__ inline uint_t rtn_bf16(float f) {
  uint_t u = __float_as_uint(f);
  return (u + 0x7FFFu + ((u >> 16) & 1u)) >> 16;
}

// Split float4 into hi/lo bf16 quads packed as uint2 each.
__device__ inline void split4(float4 f, uint2& h2, uint2& l2) {
  float ff[4] = {f.x, f.y, f.z, f.w};
  uint_t h[4], l[4];
  #pragma unroll
  for (int i = 0; i < 4; i++) {
    h[i] = rtn_bf16(ff[i]);
    float hf = __uint_as_float(h[i] << 16);
    l[i] = rtn_bf16(ff[i] - hf);
  }
  h2.x = h[0] | (h[1] << 16); h2.y = h[2] | (h[3] << 16);
  l2.x = l[0] | (l[1] << 16); l2.y = l[2] | (l[3] << 16);
}

// ---------------------------------------------------------------------------
// Weight prep: W fp32 [K][N] row-major  ->  hi/lo bf16 [N][K] row-major.
// Grid: (N/64, K/64), 256 threads. Thread handles one n, 16 consecutive k.
// ---------------------------------------------------------------------------
__global__ __launch_bounds__(256) void prep_w(
    const float* __restrict__ W, ushort_t* __restrict__ hi,
    ushort_t* __restrict__ lo, int K, int N) {
  const int t = threadIdx.x;
  const int n = blockIdx.x * 64 + (t >> 2);
  const int kq = blockIdx.y * 64 + (t & 3) * 16;
  uint_t hb[8], lb[8];
  #pragma unroll
  for (int j2 = 0; j2 < 8; j2++) {
    float f0 = W[(size_t)(kq + 2 * j2) * N + n];
    float f1 = W[(size_t)(kq + 2 * j2 + 1) * N + n];
    uint_t h0 = rtn_bf16(f0), h1 = rtn_bf16(f1);
    uint_t l0 = rtn_bf16(f0 - __uint_as_float(h0 << 16));
    uint_t l1 = rtn_bf16(f1 - __uint_as_float(h1 << 16));
    hb[j2] = h0 | (h1 << 16);
    lb[j2] = l0 | (l1 << 16);
  }
  uint4* hp = reinterpret_cast<uint4*>(&hi[(size_t)n * K + kq]);
  hp[0] = make_uint4(hb[0], hb[1], hb[2], hb[3]);
  hp[1] = make_uint4(hb[4], hb[5], hb[6], hb[7]);
  uint4* lp = reinterpret_cast<uint4*>(&lo[(size_t)n * K + kq]);
  lp[0] = make_uint4(lb[0], lb[1], lb[2], lb[3]);
  lp[1] = make_uint4(lb[4], lb[5], lb[6], lb[7]);
}

// ---------------------------------------------------------------------------
// Split-precision bf16 MFMA GEMM: C[M,N] = A[M,K] @ W[K,N] + bias.
// A fp32 (split on the fly); W pre-split as hi/lo bf16 [N][K].
// 128x128 tile, BK=32, 256 thr = 4 waves (2x2 of 64x64), 4x4 16x16 frags.
// 3 MFMA passes: hi*hi + hi*lo + lo*hi  (fp32 accumulate).
// ---------------------------------------------------------------------------
template <int ACT>  // 0 none, 1 exact GELU
__global__ __launch_bounds__(256) void gemm_mfma(
    const float* __restrict__ A, const ushort_t* __restrict__ Whi,
    const ushort_t* __restrict__ Wlo, const float* __restrict__ bias,
    float* __restrict__ C, int M, int N, int K) {
  __shared__ ushort_t Ah[128][40], Al[128][40], Bh[128][40], Bl[128][40];
  const int tid = threadIdx.x;
  const int m0 = blockIdx.y * 128;
  const int n0 = blockIdx.x * 128;
  const int lane = tid & 63;
  const int wid = tid >> 6;
  const int wr = wid >> 1, wc = wid & 1;
  const int lr = lane & 15;
  const int lk8 = (lane >> 4) * 8;

  f32x4 acc[4][4];
  #pragma unroll
  for (int i = 0; i < 4; i++)
    #pragma unroll
    for (int j = 0; j < 4; j++) acc[i][j] = (f32x4){0.f, 0.f, 0.f, 0.f};

  for (int k0 = 0; k0 < K; k0 += 32) {
    __syncthreads();
    #pragma unroll
    for (int p = 0; p < 4; p++) {
      const int row = (tid >> 3) + 32 * p;
      const int c4 = (tid & 7) * 4;
      float4 a4 = *reinterpret_cast<const float4*>(&A[(size_t)(m0 + row) * K + k0 + c4]);
      uint2 h2, l2; split4(a4, h2, l2);
      *reinterpret_cast<uint2*>(&Ah[row][c4]) = h2;
      *reinterpret_cast<uint2*>(&Al[row][c4]) = l2;
    }
    #pragma unroll
    for (int p = 0; p < 2; p++) {
      const int n = (tid >> 2) + 64 * p;
      const int c8 = (tid & 3) * 8;
      const size_t off = (size_t)(n0 + n) * K + k0 + c8;
      *reinterpret_cast<uint4*>(&Bh[n][c8]) = *reinterpret_cast<const uint4*>(&Whi[off]);
      *reinterpret_cast<uint4*>(&Bl[n][c8]) = *reinterpret_cast<const uint4*>(&Wlo[off]);
    }
    __syncthreads();

    bf16x8 ah[4], al[4], bh[4], bl[4];
    #pragma unroll
    for (int mi = 0; mi < 4; mi++) {
      const int r = wr * 64 + mi * 16 + lr;
      ah[mi] = *reinterpret_cast<const bf16x8*>(&Ah[r][lk8]);
      al[mi] = *reinterpret_cast<const bf16x8*>(&Al[r][lk8]);
    }
    #pragma unroll
    for (int nj = 0; nj < 4; nj++) {
      const int r = wc * 64 + nj * 16 + lr;
      bh[nj] = *reinterpret_cast<const bf16x8*>(&Bh[r][lk8]);
      bl[nj] = *reinterpret_cast<const bf16x8*>(&Bl[r][lk8]);
    }
    #pragma unroll
    for (int mi = 0; mi < 4; mi++)
      #pragma unroll
      for (int nj = 0; nj < 4; nj++) {
        acc[mi][nj] = __builtin_amdgcn_mfma_f32_16x16x32_bf16(ah[mi], bh[nj], acc[mi][nj], 0, 0, 0);
        acc[mi][nj] = __builtin_amdgcn_mfma_f32_16x16x32_bf16(ah[mi], bl[nj], acc[mi][nj], 0, 0, 0);
        acc[mi][nj] = __builtin_amdgcn_mfma_f32_16x16x32_bf16(al[mi], bh[nj], acc[mi][nj], 0, 0, 0);
      }
  }

  // Epilogue: C row = m0 + wr*64 + mi*16 + 4*(lane>>4) + r ; col = n0 + wc*64 + nj*16 + lr
  #pragma unroll
  for (int mi = 0; mi < 4; mi++)
    #pragma unroll
    for (int nj = 0; nj < 4; nj++) {
      const int col = n0 + wc * 64 + nj * 16 + lr;
      const float bb = bias[col];
      #pragma unroll
      for (int r = 0; r < 4; r++) {
        const int row = m0 + wr * 64 + mi * 16 + ((lane >> 4) << 2) + r;
        float v = acc[mi][nj][r] + bb;
        if (ACT == 1) v = 0.5f * v * (1.0f + erff(v * 0.70710678118654752f));
        C[(size_t)row * N + col] = v;
      }
    }
}

// ---------------------------------------------------------------------------
// Gate GEMM (split-precision MFMA): g = sigmoid([X|Y] @ Wg + bg),
// FUS[b*1024 + seg*512 + s] = X + g*Y.  X,Y: [4096][1024], Wg hi/lo [1024][2048].
// ---------------------------------------------------------------------------
__global__ __launch_bounds__(256) void gemm_gate_mfma(
    const float* __restrict__ X, const float* __restrict__ Y,
    const ushort_t* __restrict__ Whi, const ushort_t* __restrict__ Wlo,
    const float* __restrict__ bias, float* __restrict__ FUS, int seg) {
  const int N = 1024, K = 2048;
  __shared__ ushort_t Ah[128][40], Al[128][40], Bh[128][40], Bl[128][40];
  const int tid = threadIdx.x;
  const int m0 = blockIdx.y * 128;
  const int n0 = blockIdx.x * 128;
  const int lane = tid & 63;
  const int wid = tid >> 6;
  const int wr = wid >> 1, wc = wid & 1;
  const int lr = lane & 15;
  const int lk8 = (lane >> 4) * 8;

  f32x4 acc[4][4];
  #pragma unroll
  for (int i = 0; i < 4; i++)
    #pragma unroll
    for (int j = 0; j < 4; j++) acc[i][j] = (f32x4){0.f, 0.f, 0.f, 0.f};

  for (int k0 = 0; k0 < K; k0 += 32) {
    const float* Ap = (k0 < 1024) ? X : Y;
    const int kb = (k0 < 1024) ? k0 : k0 - 1024;
    __syncthreads();
    #pragma unroll
    for (int p = 0; p < 4; p++) {
      const int row = (tid >> 3) + 32 * p;
      const int c4 = (tid & 7) * 4;
      float4 a4 = *reinterpret_cast<const float4*>(&Ap[(size_t)(m0 + row) * 1024 + kb + c4]);
      uint2 h2, l2; split4(a4, h2, l2);
      *reinterpret_cast<uint2*>(&Ah[row][c4]) = h2;
      *reinterpret_cast<uint2*>(&Al[row][c4]) = l2;
    }
    #pragma unroll
    for (int p = 0; p < 2; p++) {
      const int n = (tid >> 2) + 64 * p;
      const int c8 = (tid & 3) * 8;
      const size_t off = (size_t)(n0 + n) * K + k0 + c8;
      *reinterpret_cast<uint4*>(&Bh[n][c8]) = *reinterpret_cast<const uint4*>(&Whi[off]);
      *reinterpret_cast<uint4*>(&Bl[n][c8]) = *reinterpret_cast<const uint4*>(&Wlo[off]);
    }
    __syncthreads();

    bf16x8 ah[4], al[4], bh[4], bl[4];
    #pragma unroll
    for (int mi = 0; mi < 4; mi++) {
      const int r = wr * 64 + mi * 16 + lr;
      ah[mi] = *reinterpret_cast<const bf16x8*>(&Ah[r][lk8]);
      al[mi] = *reinterpret_cast<const bf16x8*>(&Al[r][lk8]);
    }
    #pragma unroll
    for (int nj = 0; nj < 4; nj++) {
      const int r = wc * 64 + nj * 16 + lr;
      bh[nj] = *reinterpret_cast<const bf16x8*>(&Bh[r][lk8]);
      bl[nj] = *reinterpret_cast<const bf16x8*>(&Bl[r][lk8]);
    }
    #pragma unroll
    for (int mi = 0; mi < 4; mi++)
      #pragma unroll
      for (int nj = 0; nj < 4; nj++) {
        acc[mi][nj] = __builtin_amdgcn_mfma_f32_16x16x32_bf16(ah[mi], bh[nj], acc[mi][nj], 0, 0, 0);
        acc[mi][nj] = __builtin_amdgcn_mfma_f32_16x16x32_bf16(ah[mi], bl[nj], acc[mi][nj], 0, 0, 0);
        acc[mi][nj] = __builtin_amdgcn_mfma_f32_16x16x32_bf16(al[mi], bh[nj], acc[mi][nj], 0, 0, 0);
      }
  }

  #pragma unroll
  for (int mi = 0; mi < 4; mi++)
    #pragma unroll
    for (int nj = 0; nj < 4; nj++) {
      const int col = n0 + wc * 64 + nj * 16 + lr;
      const float bb = bias[col];
      #pragma unroll
      for (int r = 0; r < 4; r++) {
        const int row = m0 + wr * 64 + mi * 16 + ((lane >> 4) << 2) + r;
        float g = acc[mi][nj][r] + bb;
        g = 1.0f / (1.0f + __expf(-g));
        const float x = X[(size_t)row * 1024 + col];
        const float y = Y[(size_t)row * 1024 + col];
        const int dr = ((row >> 9) << 10) | (seg << 9) | (row & 511);
        FUS[(size_t)dr * 1024 + col] = x + g * y;
      }
    }
}

// ---------------------------------------------------------------------------
// Tiled flash attention (fp32).  64 q-rows per block of one (b,h); 64-key
// K/V LDS tiles (time-shared); P via LDS.  #pragma unroll 2 on inner GEMM
// loops to cap register pressure (full unroll spilled: 256 VGPR + scratch).
// ---------------------------------------------------------------------------
__global__ __launch_bounds__(256) void attn_tile_f32(
    const float* __restrict__ Q, const float* __restrict__ K,
    const float* __restrict__ V, float* __restrict__ O,
    int Sq, int Sk, int seglen,
    const float* __restrict__ wsp, const float* __restrict__ wtp) {
  __shared__ float Qs[64][68];
  __shared__ float KVs[64][68];
  __shared__ float Ps[64][68];

  const int tid = threadIdx.x;
  const int ty = tid >> 4;
  const int tx = tid & 15;

  const int nqt = Sq >> 6;
  const int qt = blockIdx.x % nqt;
  const int h  = (blockIdx.x / nqt) % HEADS;
  const int b  = blockIdx.x / (nqt * HEADS);

  const size_t qbase = ((size_t)b * Sq + qt * 64) * 1024 + h * 64;
  const size_t kbase = ((size_t)b * Sk) * 1024 + h * 64;

  for (int i = tid; i < 1024; i += 256) {
    const int r = i >> 4, c4 = (i & 15) * 4;
    float4 v4 = *reinterpret_cast<const float4*>(&Q[qbase + (size_t)r * 1024 + c4]);
    Qs[r][c4 + 0] = v4.x * 0.125f;
    Qs[r][c4 + 1] = v4.y * 0.125f;
    Qs[r][c4 + 2] = v4.z * 0.125f;
    Qs[r][c4 + 3] = v4.w * 0.125f;
  }

  float m[4], l[4], acc[4][4] = {}, out[4][4] = {};
  #pragma unroll
  for (int i = 0; i < 4; i++) { m[i] = -1e30f; l[i] = 0.0f; }

  const int ntile = Sk >> 6;
  const int tps = seglen >> 6;

  for (int t = 0; t < ntile; t++) {
    const size_t kt = kbase + (size_t)t * 64 * 1024;
    __syncthreads();
    for (int i = tid; i < 1024; i += 256) {
      const int r = i >> 4, c4 = (i & 15) * 4;
      *reinterpret_cast<float4*>(&KVs[r][c4]) =
          *reinterpret_cast<const float4*>(&K[kt + (size_t)r * 1024 + c4]);
    }
    __syncthreads();

    float s[4][4] = {};
    #pragma unroll 2
    for (int d0 = 0; d0 < 64; d0 += 4) {
      float4 q4[4], k4[4];
      #pragma unroll
      for (int i = 0; i < 4; i++) q4[i] = *reinterpret_cast<const float4*>(&Qs[ty * 4 + i][d0]);
      #pragma unroll
      for (int jj = 0; jj < 4; jj++) k4[jj] = *reinterpret_cast<const float4*>(&KVs[tx + 16 * jj][d0]);
      #pragma unroll
      for (int i = 0; i < 4; i++)
        #pragma unroll
        for (int jj = 0; jj < 4; jj++) {
          s[i][jj] = fmaf(q4[i].x, k4[jj].x, s[i][jj]);
          s[i][jj] = fmaf(q4[i].y, k4[jj].y, s[i][jj]);
          s[i][jj] = fmaf(q4[i].z, k4[jj].z, s[i][jj]);
          s[i][jj] = fmaf(q4[i].w, k4[jj].w, s[i][jj]);
        }
    }
    __syncthreads();

    for (int i = tid; i < 1024; i += 256) {
      const int r = i >> 4, c4 = (i & 15) * 4;
      *reinterpret_cast<float4*>(&KVs[r][c4]) =
          *reinterpret_cast<const float4*>(&V[kt + (size_t)r * 1024 + c4]);
    }

    float corr[4];
    #pragma unroll
    for (int i = 0; i < 4; i++) {
      float rm = fmaxf(fmaxf(s[i][0], s[i][1]), fmaxf(s[i][2], s[i][3]));
      #pragma unroll
      for (int o = 1; o < 16; o <<= 1) rm = fmaxf(rm, __shfl_xor(rm, o));
      const float mn = fmaxf(m[i], rm);
      corr[i] = __expf(m[i] - mn);
      float ls = 0.0f;
      #pragma unroll
      for (int jj = 0; jj < 4; jj++) {
        s[i][jj] = __expf(s[i][jj] - mn);
        ls += s[i][jj];
      }
      #pragma unroll
      for (int o = 1; o < 16; o <<= 1) ls += __shfl_xor(ls, o);
      l[i] = l[i] * corr[i] + ls;
      m[i] = mn;
      #pragma unroll
      for (int jj = 0; jj < 4; jj++) Ps[ty * 4 + i][tx + 16 * jj] = s[i][jj];
    }
    __syncthreads();

    #pragma unroll
    for (int i = 0; i < 4; i++)
      #pragma unroll
      for (int j = 0; j < 4; j++) acc[i][j] *= corr[i];
    #pragma unroll 2
    for (int k0 = 0; k0 < 64; k0 += 4) {
      float4 p4[4], v4[4];
      #pragma unroll
      for (int i = 0; i < 4; i++) p4[i] = *reinterpret_cast<const float4*>(&Ps[ty * 4 + i][k0]);
      #pragma unroll
      for (int t2 = 0; t2 < 4; t2++) v4[t2] = *reinterpret_cast<const float4*>(&KVs[k0 + t2][tx * 4]);
      #pragma unroll
      for (int i = 0; i < 4; i++)
        #pragma unroll
        for (int j = 0; j < 4; j++) {
          float a = fmaf(p4[i].x, (&v4[0].x)[j], 0.0f);
          a = fmaf(p4[i].y, (&v4[1].x)[j], a);
          a = fmaf(p4[i].z, (&v4[2].x)[j], a);
          a = fmaf(p4[i].w, (&v4[3].x)[j], a);
          acc[i][j] += a;
        }
    }

    if (((t + 1) % tps) == 0) {
      float w = 1.0f;
      if (ntile != tps) w = ((t + 1) / tps == 1) ? *wsp : *wtp;
      #pragma unroll
      for (int i = 0; i < 4; i++) {
        const float inv = w / l[i];
        #pragma unroll
        for (int j = 0; j < 4; j++) {
          out[i][j] += acc[i][j] * inv;
          acc[i][j] = 0.0f;
        }
        m[i] = -1e30f;
        l[i] = 0.0f;
      }
    }
  }

  #pragma unroll
  for (int i = 0; i < 4; i++) {
    float4 o4;
    o4.x = out[i][0]; o4.y = out[i][1]; o4.z = out[i][2]; o4.w = out[i][3];
    *reinterpret_cast<float4*>(&O[qbase + (size_t)(ty * 4 + i) * 1024 + tx * 4]) = o4;
  }
}

// ---------------------------------------------------------------------------
// LayerNorm over 1024 cols of (X + Y).  mode 0: out[row]; mode 1: split.
// ---------------------------------------------------------------------------
__global__ __launch_bounds__(256) void ln_f32(
    const float* __restrict__ X, const float* __restrict__ Y,
    const float* __restrict__ g, const float* __restrict__ bb,
    float* __restrict__ out, int mode) {
  __shared__ float sm[4];
  const int row = blockIdx.x;
  const int tid = threadIdx.x;

  float v[4];
  #pragma unroll
  for (int i = 0; i < 4; i++) {
    const int c = tid + i * 256;
    v[i] = X[(size_t)row * 1024 + c] + Y[(size_t)row * 1024 + c];
  }
  float s = v[0] + v[1] + v[2] + v[3];
  #pragma unroll
  for (int o = 32; o >= 1; o >>= 1) s += __shfl_xor(s, o);
  if ((tid & 63) == 0) sm[tid >> 6] = s;
  __syncthreads();
  const float mu = (sm[0] + sm[1] + sm[2] + sm[3]) * (1.0f / 1024.0f);
  __syncthreads();

  float d2 = 0.0f;
  #pragma unroll
  for (int i = 0; i < 4; i++) {
    const float d = v[i] - mu;
    d2 += d * d;
  }
  #pragma unroll
  for (int o = 32; o >= 1; o >>= 1) d2 += __shfl_xor(d2, o);
  if ((tid & 63) == 0) sm[tid >> 6] = d2;
  __syncthreads();
  const float var = (sm[0] + sm[1] + sm[2] + sm[3]) * (1.0f / 1024.0f);
  const float rstd = rsqrtf(var + 1e-12f);

  float* dst;
  if (mode == 0) {
    dst = out + (size_t)row * 1024;
  } else {
    const int b = row >> 10;
    const int sdx = row & 1023;
    if (sdx < 512)
      dst = out + ((size_t)(b * 512 + sdx)) * 1024;
    else
      dst = out + (size_t)B_SZ * S_LEN * DIM + ((size_t)(b * 512 + (sdx - 512))) * 1024;
  }
  #pragma unroll
  for (int i = 0; i < 4; i++) {
    const int c = tid + i * 256;
    dst[c] = (v[i] - mu) * rstd * g[c] + bb[c];
  }
}

// ---------------------------------------------------------------------------
// Workspace = exactly 128 MiB: Buf0/1/2 (32 MB each) + 32 MB weight region.
// d_out (32 MB) doubles as scratch (cross-attn out, then self V).
// ---------------------------------------------------------------------------
extern "C" void kernel_launch(void* const* d_in, const int* in_sizes, int n_in,
                              void* d_out, int out_size, void* d_ws, size_t ws_size,
                              hipStream_t stream) {
  const float* src = (const float*)d_in[0];
  const float* tgt = (const float*)d_in[1];
  const float* Wq = (const float*)d_in[2];
  const float* bq = (const float*)d_in[3];
  const float* Wk = (const float*)d_in[4];
  const float* bk = (const float*)d_in[5];
  const float* Wv = (const float*)d_in[6];
  const float* bv = (const float*)d_in[7];
  const float* Wd = (const float*)d_in[8];
  const float* bd = (const float*)d_in[9];
  const float* ln1g = (const float*)d_in[10];
  const float* ln1b = (const float*)d_in[11];
  const float* wsp = (const float*)d_in[12];
  const float* wtp = (const float*)d_in[13];
  const float* Wgs = (const float*)d_in[14];
  const float* bgs = (const float*)d_in[15];
  const float* Wgt = (const float*)d_in[16];
  const float* bgt = (const float*)d_in[17];
  const float* W1 = (const float*)d_in[18];
  const float* b1 = (const float*)d_in[19];
  const float* W2 = (const float*)d_in[20];
  const float* b2 = (const float*)d_in[21];
  const float* ln2g = (const float*)d_in[22];
  const float* ln2b = (const float*)d_in[23];

  const size_t M1 = (size_t)4096 * 1024;     // half-buffer (floats)
  const size_t BUF = 2 * M1;                 // [8192][1024] floats
  float* Buf0 = (float*)d_ws;
  float* Buf1 = Buf0 + BUF;
  float* Buf2 = Buf1 + BUF;
  ushort_t* wt = (ushort_t*)(Buf2 + BUF);    // 16M ushorts = 32 MB
  float* DOUT = (float*)d_out;

  const size_t MU = (size_t)1024 * 1024;
  ushort_t* Qh = wt;            ushort_t* Ql = wt + 1 * MU;
  ushort_t* Kh = wt + 2 * MU;   ushort_t* Kl = wt + 3 * MU;
  ushort_t* Vh = wt + 4 * MU;   ushort_t* Vl = wt + 5 * MU;
  ushort_t* Dh = wt + 6 * MU;   ushort_t* Dl = wt + 7 * MU;
  ushort_t* Gsh = wt + 8 * MU;  ushort_t* Gsl = wt + 10 * MU;
  ushort_t* Gth = wt + 12 * MU; ushort_t* Gtl = wt + 14 * MU;
  ushort_t* W1h = wt;           ushort_t* W1l = wt + 4 * MU;   // after Wd GEMM
  ushort_t* W2h = wt + 8 * MU;  ushort_t* W2l = wt + 12 * MU;

  const dim3 blk(256);

  // --- weight prep (QKV, Wd, gates) ---
  prep_w<<<dim3(16, 16), blk, 0, stream>>>(Wq, Qh, Ql, 1024, 1024);
  prep_w<<<dim3(16, 16), blk, 0, stream>>>(Wk, Kh, Kl, 1024, 1024);
  prep_w<<<dim3(16, 16), blk, 0, stream>>>(Wv, Vh, Vl, 1024, 1024);
  prep_w<<<dim3(16, 16), blk, 0, stream>>>(Wd, Dh, Dl, 1024, 1024);
  prep_w<<<dim3(16, 32), blk, 0, stream>>>(Wgs, Gsh, Gsl, 2048, 1024);
  prep_w<<<dim3(16, 32), blk, 0, stream>>>(Wgt, Gth, Gtl, 2048, 1024);

  // --- 1. cross projections: Q->Buf0, K->Buf1, V->Buf2 ---
  gemm_mfma<0><<<dim3(8, 32), blk, 0, stream>>>(src, Qh, Ql, bq, Buf0,      4096, 1024, 1024);
  gemm_mfma<0><<<dim3(8, 32), blk, 0, stream>>>(tgt, Qh, Ql, bq, Buf0 + M1, 4096, 1024, 1024);
  gemm_mfma<0><<<dim3(8, 32), blk, 0, stream>>>(src, Kh, Kl, bk, Buf1,      4096, 1024, 1024);
  gemm_mfma<0><<<dim3(8, 32), blk, 0, stream>>>(tgt, Kh, Kl, bk, Buf1 + M1, 4096, 1024, 1024);
  gemm_mfma<0><<<dim3(8, 32), blk, 0, stream>>>(src, Vh, Vl, bv, Buf2,      4096, 1024, 1024);
  gemm_mfma<0><<<dim3(8, 32), blk, 0, stream>>>(tgt, Vh, Vl, bv, Buf2 + M1, 4096, 1024, 1024);

  // --- 2. cross attention: s_t -> DOUT lower, t_s -> DOUT upper ---
  const int xblocks = B_SZ * HEADS * (512 / 64);
  attn_tile_f32<<<xblocks, blk, 0, stream>>>(Buf0,      Buf1 + M1, Buf2 + M1, DOUT,      512, 512, 512, wsp, wtp);
  attn_tile_f32<<<xblocks, blk, 0, stream>>>(Buf0 + M1, Buf1,      Buf2,      DOUT + M1, 512, 512, 512, wsp, wtp);

  // --- 3. gates + residual -> FUS in Buf0 ---
  gemm_gate_mfma<<<dim3(8, 32), blk, 0, stream>>>(src, DOUT,      Gsh, Gsl, bgs, Buf0, 0);
  gemm_gate_mfma<<<dim3(8, 32), blk, 0, stream>>>(tgt, DOUT + M1, Gth, Gtl, bgt, Buf0, 1);

  // --- 4. self projections: q->Buf1, k->Buf2, v->DOUT ---
  gemm_mfma<0><<<dim3(8, 64), blk, 0, stream>>>(Buf0, Qh, Ql, bq, Buf1, 8192, 1024, 1024);
  gemm_mfma<0><<<dim3(8, 64), blk, 0, stream>>>(Buf0, Kh, Kl, bk, Buf2, 8192, 1024, 1024);
  gemm_mfma<0><<<dim3(8, 64), blk, 0, stream>>>(Buf0, Vh, Vl, bv, DOUT, 8192, 1024, 1024);

  // --- 5. self attention, in-place over q (each block reads only its own
  //        q-slice before writing it) ---
  const int sblocks = B_SZ * HEADS * (1024 / 64);
  attn_tile_f32<<<sblocks, blk, 0, stream>>>(Buf1, Buf2, DOUT, Buf1, 1024, 1024, 512, wsp, wtp);

  // --- 6. ctx = attn_out @ Wd -> Buf2 ---
  gemm_mfma<0><<<dim3(8, 64), blk, 0, stream>>>(Buf1, Dh, Dl, bd, Buf2, 8192, 1024, 1024);

  // --- weight prep (MLP) — QKV/Wd/gate weights dead now ---
  prep_w<<<dim3(64, 16), blk, 0, stream>>>(W1, W1h, W1l, 1024, 4096);
  prep_w<<<dim3(16, 64), blk, 0, stream>>>(W2, W2h, W2l, 4096, 1024);

  // --- 7. hidden = LN1(ctx + fused) -> Buf1 ---
  ln_f32<<<8192, blk, 0, stream>>>(Buf2, Buf0, ln1g, ln1b, Buf1, 0);

  // --- 8. MLP chunked (4 x 2048 rows): mid -> Buf0, ff -> Buf2 ---
  for (int ch = 0; ch < 4; ch++) {
    const size_t ro = (size_t)ch * 2048 * 1024;
    gemm_mfma<1><<<dim3(32, 16), blk, 0, stream>>>(Buf1 + ro, W1h, W1l, b1, Buf0, 2048, 4096, 1024);
    gemm_mfma<0><<<dim3(8, 16), blk, 0, stream>>>(Buf0, W2h, W2l, b2, Buf2 + ro, 2048, 1024, 4096);
  }

  // --- 9. LN2(ff + hidden) -> split outputs ---
  ln_f32<<<8192, blk, 0, stream>>>(Buf2, Buf1, ln2g, ln2b, DOUT, 1);
}